// Round 1
// baseline (1609.778 us; speedup 1.0000x reference)
//
#include <hip/hip_runtime.h>

typedef unsigned int uint;
typedef unsigned short ushort;

typedef short short8 __attribute__((ext_vector_type(8)));
typedef float floatx4 __attribute__((ext_vector_type(4)));

#define FIN 512
#define HF  128
#define NC  40
#define KHOPS 10

__device__ __forceinline__ ushort f2bf(float f) {
    uint u = __float_as_uint(f);
    uint r = (u + 0x7fffu + ((u >> 16) & 1u)) >> 16;
    return (ushort)r;
}
__device__ __forceinline__ float bflo(uint v) { return __uint_as_float(v << 16); }
__device__ __forceinline__ float bfhi(uint v) { return __uint_as_float(v & 0xffff0000u); }
__device__ __forceinline__ uint packbf2(float a, float b) {
    return (uint)f2bf(a) | ((uint)f2bf(b) << 16);
}
__device__ __forceinline__ float selu_f(float v) {
    const float l = 1.0507009873554805f, a = 1.6732632423543772f;
    return v > 0.f ? l * v : l * a * (expf(v) - 1.f);
}

// ---------------- W1 -> MFMA fragment layout (bf16) ----------------
// w1f[((s*8+t)*64+l)*8 + i] = W1[s*32 + (l>>4)*8 + i][t*16 + (l&15)]
__global__ void k_w1frag(const float* __restrict__ W1, ushort* __restrict__ w1f) {
    int id = blockIdx.x * 256 + threadIdx.x;
    if (id >= 16 * 8 * 64) return;
    int l = id & 63;
    int t = (id >> 6) & 7;
    int s = id >> 9;
    int row0 = s * 32 + (l >> 4) * 8;
    int col  = t * 16 + (l & 15);
    ushort* dst = w1f + (size_t)id * 8;
#pragma unroll
    for (int i = 0; i < 8; ++i)
        dst[i] = f2bf(W1[(row0 + i) * HF + col]);
}

// ---------------- h = selu(x@W1+b1), bf16 out -> hops[0] ----------------
__global__ void k_gemm(const float* __restrict__ x, const ushort* __restrict__ w1f,
                       const float* __restrict__ b1, ushort* __restrict__ h, int N) {
    __shared__ __align__(16) ushort As[64 * 64];  // [64 rows][64 k] bf16, XOR-swizzled 16B slots
    int tid = threadIdx.x;
    int lane = tid & 63, w = tid >> 6;
    int rowblk = blockIdx.x * 64;

    floatx4 acc[8];
#pragma unroll
    for (int t = 0; t < 8; ++t) acc[t] = (floatx4){0.f, 0.f, 0.f, 0.f};

    for (int kk = 0; kk < 8; ++kk) {
        // stage 64x64 f32 tile of x as bf16 into LDS
#pragma unroll
        for (int i = 0; i < 4; ++i) {
            int li = tid + 256 * i;          // 0..1023
            int r = li >> 4, c4 = li & 15;   // row, float4-column
            float4 v = make_float4(0.f, 0.f, 0.f, 0.f);
            if (rowblk + r < N)
                v = *(const float4*)(x + (size_t)(rowblk + r) * FIN + kk * 64 + c4 * 4);
            uint p0 = packbf2(v.x, v.y);
            uint p1 = packbf2(v.z, v.w);
            int byteoff = (r * 128 + c4 * 8) ^ ((r & 7) << 4);
            *(uint2*)((char*)As + byteoff) = make_uint2(p0, p1);
        }
        __syncthreads();
        int rowA = w * 16 + (lane & 15);
#pragma unroll
        for (int s = 0; s < 2; ++s) {
            int aoff = (rowA * 128 + s * 64 + (lane >> 4) * 16) ^ ((rowA & 7) << 4);
            short8 af = *(const short8*)((const char*)As + aoff);
#pragma unroll
            for (int t = 0; t < 8; ++t) {
                const short8 bf = *(const short8*)(w1f + ((size_t)((kk * 2 + s) * 8 + t) * 64 + lane) * 8);
                acc[t] = __builtin_amdgcn_mfma_f32_16x16x32_bf16(af, bf, acc[t], 0, 0, 0);
            }
        }
        __syncthreads();
    }
    // epilogue: D layout col=lane&15, row=(lane>>4)*4+q
#pragma unroll
    for (int t = 0; t < 8; ++t) {
        int col = t * 16 + (lane & 15);
        float bias = b1[col];
#pragma unroll
        for (int q = 0; q < 4; ++q) {
            int row = rowblk + w * 16 + (lane >> 4) * 4 + q;
            if (row < N) {
                float v = selu_f(acc[t][q] + bias);
                h[(size_t)row * HF + col] = f2bf(v);
            }
        }
    }
}

// ---------------- degree / dinv ----------------
__global__ void k_deg_init(int* __restrict__ deg, int N) {
    int i = blockIdx.x * 256 + threadIdx.x;
    if (i < N) deg[i] = 1;  // self loop
}
__global__ void k_deg(const int* __restrict__ ei, int* __restrict__ deg, int E) {
    int e = blockIdx.x * 256 + threadIdx.x;
    if (e < E) atomicAdd(&deg[ei[E + e]], 1);
}
__global__ void k_dinv(const int* __restrict__ deg, float* __restrict__ dinv, int N) {
    int i = blockIdx.x * 256 + threadIdx.x;
    if (i < N) dinv[i] = rsqrtf((float)deg[i]);
}

// ---------------- exclusive scan of (deg-1) -> offsets ----------------
__global__ void k_scan1(const int* __restrict__ deg, int* __restrict__ offs,
                        int* __restrict__ bsum, int N) {
    __shared__ int lds[256];
    int tid = threadIdx.x;
    int base = blockIdx.x * 1024;
    int c[4], s = 0;
#pragma unroll
    for (int i = 0; i < 4; ++i) {
        int g = base + tid * 4 + i;
        c[i] = (g < N) ? (deg[g] - 1) : 0;
        s += c[i];
    }
    lds[tid] = s;
    __syncthreads();
    for (int off = 1; off < 256; off <<= 1) {
        int add = (tid >= off) ? lds[tid - off] : 0;
        __syncthreads();
        lds[tid] += add;
        __syncthreads();
    }
    int run = lds[tid] - s;  // exclusive for this thread
#pragma unroll
    for (int i = 0; i < 4; ++i) {
        int g = base + tid * 4 + i;
        if (g < N) offs[g] = run;
        run += c[i];
    }
    if (tid == 0) bsum[blockIdx.x] = lds[255];
}
__global__ void k_scan2(int* __restrict__ bsum, int nb) {
    if (blockIdx.x == 0 && threadIdx.x == 0) {
        int run = 0;
        for (int i = 0; i < nb; ++i) { int v = bsum[i]; bsum[i] = run; run += v; }
    }
}
__global__ void k_scan3(int* __restrict__ offs, const int* __restrict__ bsum, int N, int E) {
    int g = blockIdx.x * 256 + threadIdx.x;
    if (g < N) offs[g] += bsum[g >> 10];
    else if (g == N) offs[N] = E;
}

// ---------------- CSR fill ----------------
__global__ void k_fill(const int* __restrict__ ei, const int* __restrict__ offs,
                       int* __restrict__ cursor, int* __restrict__ csrc,
                       float* __restrict__ cw, const float* __restrict__ dinv, int E) {
    int e = blockIdx.x * 256 + threadIdx.x;
    if (e >= E) return;
    int r = ei[e], c = ei[E + e];
    int p = offs[c] + atomicAdd(&cursor[c], 1);
    csrc[p] = r;
    cw[p] = dinv[r] * dinv[c];
}

// ---------------- feature_pool[0] from h ----------------
__global__ void k_fp0(const ushort* __restrict__ h, const float* __restrict__ projw,
                      const float* __restrict__ projb, float* __restrict__ fp0, int N) {
    int wid = (blockIdx.x * blockDim.x + threadIdx.x) >> 6;
    int lane = threadIdx.x & 63;
    if (wid >= N) return;
    uint v = ((const uint*)h)[(size_t)wid * 64 + lane];
    float dot = bflo(v) * projw[2 * lane] + bfhi(v) * projw[2 * lane + 1];
#pragma unroll
    for (int m = 1; m < 64; m <<= 1) dot += __shfl_xor(dot, m);
    if (lane == 0) fp0[wid] = dot + projb[0];
}

// ---------------- one hop: xn = A_hat @ xc (CSR gather), + feature_pool ----------------
__global__ void k_hop(const ushort* __restrict__ xin, ushort* __restrict__ xout,
                      const int* __restrict__ offs, const int* __restrict__ csrc,
                      const float* __restrict__ cw, const float* __restrict__ dinv,
                      const float* __restrict__ projw, const float* __restrict__ projb,
                      float* __restrict__ fpk, int N) {
    int wid = (blockIdx.x * blockDim.x + threadIdx.x) >> 6;
    int lane = threadIdx.x & 63;
    if (wid >= N) return;
    const uint* xin2 = (const uint*)xin;
    float dn = dinv[wid];
    uint sv = xin2[(size_t)wid * 64 + lane];
    float wself = dn * dn;
    float acc0 = wself * bflo(sv);
    float acc1 = wself * bfhi(sv);
    int s = offs[wid], e = offs[wid + 1];
    for (int base = s; base < e; base += 64) {
        int cnt = min(64, e - base);
        int idx = base + lane;
        int src = (idx < e) ? csrc[idx] : 0;
        float ew = (idx < e) ? cw[idx] : 0.f;
        for (int j = 0; j < cnt; ++j) {
            int sj = __shfl(src, j);
            float wj = __shfl(ew, j);
            uint xv = xin2[(size_t)sj * 64 + lane];
            acc0 = fmaf(wj, bflo(xv), acc0);
            acc1 = fmaf(wj, bfhi(xv), acc1);
        }
    }
    ((uint*)xout)[(size_t)wid * 64 + lane] = packbf2(acc0, acc1);
    float dot = acc0 * projw[2 * lane] + acc1 * projw[2 * lane + 1];
#pragma unroll
    for (int m = 1; m < 64; m <<= 1) dot += __shfl_xor(dot, m);
    if (lane == 0) fpk[wid] = dot + projb[0];
}

// ---------------- mean of feature_pool over nodes ----------------
__global__ void k_msum(const float* __restrict__ fp, float* __restrict__ msum, int N) {
    int k = blockIdx.y;
    int i = blockIdx.x * 256 + threadIdx.x;
    int tid = threadIdx.x;
    float v = (i < N) ? fp[(size_t)k * N + i] : 0.f;
#pragma unroll
    for (int m = 1; m < 64; m <<= 1) v += __shfl_xor(v, m);
    __shared__ float ws4[4];
    if ((tid & 63) == 0) ws4[tid >> 6] = v;
    __syncthreads();
    if (tid == 0) atomicAdd(&msum[k], ws4[0] + ws4[1] + ws4[2] + ws4[3]);
}

// ---------------- share_w = l2norm(mean + hop_w) ----------------
__global__ void k_sharew(const float* __restrict__ msum, const float* __restrict__ hopw,
                         float* __restrict__ sharew, int N) {
    int k = threadIdx.x;
    float s = (k < KHOPS + 1) ? (msum[k] / (float)N + hopw[k]) : 0.f;
    float ss = s * s;
#pragma unroll
    for (int m = 1; m < 64; m <<= 1) ss += __shfl_xor(ss, m);
    float inv = 1.f / fmaxf(sqrtf(ss), 1e-12f);
    if (k < KHOPS + 1) sharew[k] = s * inv;
}

// ---------------- final: combine hops, tanh, W2, log_softmax ----------------
__global__ void k_final(const ushort* __restrict__ hops, const float* __restrict__ fp,
                        const float* __restrict__ sharew, const float* __restrict__ W2,
                        const float* __restrict__ b2, float* __restrict__ out, int N) {
    int wid = (blockIdx.x * blockDim.x + threadIdx.x) >> 6;
    int lane = threadIdx.x & 63;
    if (wid >= N) return;
    const uint* hops2 = (const uint*)hops;

    float c[KHOPS + 1];
    float ss = 0.f;
#pragma unroll
    for (int k = 0; k < KHOPS + 1; ++k) {
        float f = fp[(size_t)k * N + wid];
        c[k] = f;
        ss += f * f;
    }
    float inv = 1.f / fmaxf(sqrtf(ss), 1e-12f);
#pragma unroll
    for (int k = 0; k < KHOPS + 1; ++k)
        c[k] = 0.2f * sharew[k] + 0.8f * c[k] * inv;

    float o0 = 0.f, o1 = 0.f;
#pragma unroll
    for (int k = 0; k < KHOPS + 1; ++k) {
        uint v = hops2[(size_t)k * N * 64 + (size_t)wid * 64 + lane];
        o0 = fmaf(c[k], bflo(v), o0);
        o1 = fmaf(c[k], bfhi(v), o1);
    }
    float h0 = tanhf(o0), h1 = tanhf(o1);

    int cc = lane < NC ? lane : NC - 1;
    float logit = 0.f;
#pragma unroll
    for (int l2 = 0; l2 < 64; ++l2) {
        float ha = __shfl(h0, l2);
        float hb = __shfl(h1, l2);
        logit = fmaf(ha, W2[(2 * l2) * NC + cc], logit);
        logit = fmaf(hb, W2[(2 * l2 + 1) * NC + cc], logit);
    }
    logit += b2[cc];
    float lm = (lane < NC) ? logit : -INFINITY;
#pragma unroll
    for (int m = 1; m < 64; m <<= 1) lm = fmaxf(lm, __shfl_xor(lm, m));
    float ex = (lane < NC) ? expf(logit - lm) : 0.f;
    float se = ex;
#pragma unroll
    for (int m = 1; m < 64; m <<= 1) se += __shfl_xor(se, m);
    float ls = logit - lm - logf(se);
    if (lane < NC) out[(size_t)wid * NC + lane] = ls;
}

// ---------------- launch ----------------
extern "C" void kernel_launch(void* const* d_in, const int* in_sizes, int n_in,
                              void* d_out, int out_size, void* d_ws, size_t ws_size,
                              hipStream_t stream) {
    const float* x     = (const float*)d_in[0];
    const int*   ei    = (const int*)d_in[1];
    const float* W1    = (const float*)d_in[2];
    const float* b1    = (const float*)d_in[3];
    const float* projw = (const float*)d_in[4];
    const float* projb = (const float*)d_in[5];
    const float* hopw  = (const float*)d_in[6];
    const float* W2    = (const float*)d_in[7];
    const float* b2    = (const float*)d_in[8];
    float* out = (float*)d_out;

    int N = in_sizes[0] / FIN;
    int E = in_sizes[1] / 2;

    char* p = (char*)d_ws;
    auto alloc = [&](size_t bytes) -> char* {
        char* r = p;
        p += (bytes + 255) & ~(size_t)255;
        return r;
    };
    ushort* hops   = (ushort*)alloc((size_t)(KHOPS + 1) * N * HF * 2);
    int*    deg    = (int*)alloc((size_t)N * 4);
    float*  dinv   = (float*)alloc((size_t)N * 4);
    int*    offs   = (int*)alloc((size_t)(N + 1) * 4);
    int*    cursor = (int*)alloc((size_t)N * 4);
    int*    bsum   = (int*)alloc(4096);
    int*    csrc   = (int*)alloc((size_t)E * 4);
    float*  cw     = (float*)alloc((size_t)E * 4);
    float*  fp     = (float*)alloc((size_t)(KHOPS + 1) * N * 4);
    float*  msum   = (float*)alloc(64);
    float*  sharew = (float*)alloc(64);
    ushort* w1f    = (ushort*)alloc((size_t)FIN * HF * 2);

    int nb256N = (N + 255) / 256;
    int nbE    = (E + 255) / 256;
    int nbWave = (N + 3) / 4;        // 1 wave per node, 4 waves/block
    int nb1024 = (N + 1023) / 1024;  // scan blocks

    // W1 fragment shuffle + GEMM (h -> hops[0])
    k_w1frag<<<32, 256, 0, stream>>>(W1, w1f);
    k_gemm<<<(N + 63) / 64, 256, 0, stream>>>(x, w1f, b1, hops, N);

    // degrees / dinv
    k_deg_init<<<nb256N, 256, 0, stream>>>(deg, N);
    k_deg<<<nbE, 256, 0, stream>>>(ei, deg, E);
    k_dinv<<<nb256N, 256, 0, stream>>>(deg, dinv, N);

    // CSR offsets (exclusive scan of deg-1)
    k_scan1<<<nb1024, 256, 0, stream>>>(deg, offs, bsum, N);
    k_scan2<<<1, 64, 0, stream>>>(bsum, nb1024);
    k_scan3<<<(N + 256) / 256, 256, 0, stream>>>(offs, bsum, N, E);

    // CSR fill
    hipMemsetAsync(cursor, 0, (size_t)N * 4, stream);
    k_fill<<<nbE, 256, 0, stream>>>(ei, offs, cursor, csrc, cw, dinv, E);

    // feature_pool[0]
    k_fp0<<<nbWave, 256, 0, stream>>>(hops, projw, projb, fp, N);

    // K hops
    for (int k = 1; k <= KHOPS; ++k) {
        const ushort* xin = hops + (size_t)(k - 1) * N * HF;
        ushort* xout      = hops + (size_t)k * N * HF;
        k_hop<<<nbWave, 256, 0, stream>>>(xin, xout, offs, csrc, cw, dinv,
                                          projw, projb, fp + (size_t)k * N, N);
    }

    // share_w
    hipMemsetAsync(msum, 0, 64, stream);
    dim3 gm(nb256N, KHOPS + 1);
    k_msum<<<gm, 256, 0, stream>>>(fp, msum, N);
    k_sharew<<<1, 64, 0, stream>>>(msum, hopw, sharew, N);

    // final
    k_final<<<nbWave, 256, 0, stream>>>(hops, fp, sharew, W2, b2, out, N);
}

// Round 2
// 1229.366 us; speedup vs baseline: 1.3094x; 1.3094x over previous
//
#include <hip/hip_runtime.h>

typedef unsigned int uint;
typedef unsigned short ushort;

typedef short short8 __attribute__((ext_vector_type(8)));
typedef float floatx4 __attribute__((ext_vector_type(4)));

#define FIN 512
#define HF  128
#define NC  40
#define KHOPS 10

__device__ __forceinline__ ushort f2bf(float f) {
    uint u = __float_as_uint(f);
    uint r = (u + 0x7fffu + ((u >> 16) & 1u)) >> 16;
    return (ushort)r;
}
__device__ __forceinline__ float bflo(uint v) { return __uint_as_float(v << 16); }
__device__ __forceinline__ float bfhi(uint v) { return __uint_as_float(v & 0xffff0000u); }
__device__ __forceinline__ uint packbf2(float a, float b) {
    return (uint)f2bf(a) | ((uint)f2bf(b) << 16);
}
__device__ __forceinline__ float selu_f(float v) {
    const float l = 1.0507009873554805f, a = 1.6732632423543772f;
    return v > 0.f ? l * v : l * a * (expf(v) - 1.f);
}

// ---------------- W1 -> MFMA fragment layout (bf16) ----------------
__global__ void k_w1frag(const float* __restrict__ W1, ushort* __restrict__ w1f) {
    int id = blockIdx.x * 256 + threadIdx.x;
    if (id >= 16 * 8 * 64) return;
    int l = id & 63;
    int t = (id >> 6) & 7;
    int s = id >> 9;
    int row0 = s * 32 + (l >> 4) * 8;
    int col  = t * 16 + (l & 15);
    ushort* dst = w1f + (size_t)id * 8;
#pragma unroll
    for (int i = 0; i < 8; ++i)
        dst[i] = f2bf(W1[(row0 + i) * HF + col]);
}

// ---------------- W2 -> MFMA fragment layout (bf16, 48-col padded) ----------------
// w2f[((kk*3+t)*64+l)*8 + i] = W2[kk*32 + (l>>4)*8 + i][t*16 + (l&15)]  (0 if col>=40)
__global__ void k_w2frag(const float* __restrict__ W2, ushort* __restrict__ w2f) {
    int id = blockIdx.x * 256 + threadIdx.x;
    if (id >= 12 * 64) return;
    int l = id & 63;
    int tile = id >> 6;        // kk*3 + t
    int kk = tile / 3, t = tile % 3;
    int row0 = kk * 32 + (l >> 4) * 8;
    int col  = t * 16 + (l & 15);
    ushort* dst = w2f + (size_t)id * 8;
#pragma unroll
    for (int i = 0; i < 8; ++i)
        dst[i] = (col < NC) ? f2bf(W2[(row0 + i) * NC + col]) : (ushort)0;
}

// ---------------- h = selu(x@W1+b1), bf16 out -> hops[0] ----------------
__global__ void k_gemm(const float* __restrict__ x, const ushort* __restrict__ w1f,
                       const float* __restrict__ b1, ushort* __restrict__ h, int N) {
    __shared__ __align__(16) ushort As[64 * 64];
    int tid = threadIdx.x;
    int lane = tid & 63, w = tid >> 6;
    int rowblk = blockIdx.x * 64;

    floatx4 acc[8];
#pragma unroll
    for (int t = 0; t < 8; ++t) acc[t] = (floatx4){0.f, 0.f, 0.f, 0.f};

    for (int kk = 0; kk < 8; ++kk) {
#pragma unroll
        for (int i = 0; i < 4; ++i) {
            int li = tid + 256 * i;
            int r = li >> 4, c4 = li & 15;
            float4 v = make_float4(0.f, 0.f, 0.f, 0.f);
            if (rowblk + r < N)
                v = *(const float4*)(x + (size_t)(rowblk + r) * FIN + kk * 64 + c4 * 4);
            uint p0 = packbf2(v.x, v.y);
            uint p1 = packbf2(v.z, v.w);
            int byteoff = (r * 128 + c4 * 8) ^ ((r & 7) << 4);
            *(uint2*)((char*)As + byteoff) = make_uint2(p0, p1);
        }
        __syncthreads();
        int rowA = w * 16 + (lane & 15);
#pragma unroll
        for (int s = 0; s < 2; ++s) {
            int aoff = (rowA * 128 + s * 64 + (lane >> 4) * 16) ^ ((rowA & 7) << 4);
            short8 af = *(const short8*)((const char*)As + aoff);
#pragma unroll
            for (int t = 0; t < 8; ++t) {
                const short8 bf = *(const short8*)(w1f + ((size_t)((kk * 2 + s) * 8 + t) * 64 + lane) * 8);
                acc[t] = __builtin_amdgcn_mfma_f32_16x16x32_bf16(af, bf, acc[t], 0, 0, 0);
            }
        }
        __syncthreads();
    }
#pragma unroll
    for (int t = 0; t < 8; ++t) {
        int col = t * 16 + (lane & 15);
        float bias = b1[col];
#pragma unroll
        for (int q = 0; q < 4; ++q) {
            int row = rowblk + w * 16 + (lane >> 4) * 4 + q;
            if (row < N) {
                float v = selu_f(acc[t][q] + bias);
                h[(size_t)row * HF + col] = f2bf(v);
            }
        }
    }
}

// ---------------- degree / dinv ----------------
__global__ void k_deg_init(int* __restrict__ deg, int N) {
    int i = blockIdx.x * 256 + threadIdx.x;
    if (i < N) deg[i] = 1;
}
__global__ void k_deg(const int* __restrict__ ei, int* __restrict__ deg, int E) {
    int e = blockIdx.x * 256 + threadIdx.x;
    if (e < E) atomicAdd(&deg[ei[E + e]], 1);
}
__global__ void k_dinv(const int* __restrict__ deg, float* __restrict__ dinv, int N) {
    int i = blockIdx.x * 256 + threadIdx.x;
    if (i < N) dinv[i] = rsqrtf((float)deg[i]);
}

// ---------------- exclusive scan of (deg-1) -> offsets ----------------
__global__ void k_scan1(const int* __restrict__ deg, int* __restrict__ offs,
                        int* __restrict__ bsum, int N) {
    __shared__ int lds[256];
    int tid = threadIdx.x;
    int base = blockIdx.x * 1024;
    int c[4], s = 0;
#pragma unroll
    for (int i = 0; i < 4; ++i) {
        int g = base + tid * 4 + i;
        c[i] = (g < N) ? (deg[g] - 1) : 0;
        s += c[i];
    }
    lds[tid] = s;
    __syncthreads();
    for (int off = 1; off < 256; off <<= 1) {
        int add = (tid >= off) ? lds[tid - off] : 0;
        __syncthreads();
        lds[tid] += add;
        __syncthreads();
    }
    int run = lds[tid] - s;
#pragma unroll
    for (int i = 0; i < 4; ++i) {
        int g = base + tid * 4 + i;
        if (g < N) offs[g] = run;
        run += c[i];
    }
    if (tid == 0) bsum[blockIdx.x] = lds[255];
}
__global__ void k_scan2(int* __restrict__ bsum, int nb) {
    if (blockIdx.x == 0 && threadIdx.x == 0) {
        int run = 0;
        for (int i = 0; i < nb; ++i) { int v = bsum[i]; bsum[i] = run; run += v; }
    }
}
__global__ void k_scan3(int* __restrict__ offs, const int* __restrict__ bsum, int N, int E) {
    int g = blockIdx.x * 256 + threadIdx.x;
    if (g < N) offs[g] += bsum[g >> 10];
    else if (g == N) offs[N] = E;
}

// ---------------- CSR fill: edat = {src, bits(dinv_r*dinv_c)} ----------------
__global__ void k_fill(const int* __restrict__ ei, const int* __restrict__ offs,
                       int* __restrict__ cursor, int2* __restrict__ edat,
                       const float* __restrict__ dinv, int E) {
    int e = blockIdx.x * 256 + threadIdx.x;
    if (e >= E) return;
    int r = ei[e], c = ei[E + e];
    int p = offs[c] + atomicAdd(&cursor[c], 1);
    edat[p] = make_int2(r, __float_as_int(dinv[r] * dinv[c]));
}

// ---------------- feature_pool[0] from h ----------------
__global__ void k_fp0(const ushort* __restrict__ h, const float* __restrict__ projw,
                      const float* __restrict__ projb, float* __restrict__ fp0, int N) {
    int wid = (blockIdx.x * blockDim.x + threadIdx.x) >> 6;
    int lane = threadIdx.x & 63;
    if (wid >= N) return;
    uint v = ((const uint*)h)[(size_t)wid * 64 + lane];
    float dot = bflo(v) * projw[2 * lane] + bfhi(v) * projw[2 * lane + 1];
#pragma unroll
    for (int m = 1; m < 64; m <<= 1) dot += __shfl_xor(dot, m);
    if (lane == 0) fp0[wid] = dot + projb[0];
}

// ---------------- one hop: xn = A_hat @ xc (CSR gather via readlane/SGPR base) ----
__global__ void k_hop(const ushort* __restrict__ xin, ushort* __restrict__ xout,
                      const int* __restrict__ offs, const int2* __restrict__ edat,
                      const float* __restrict__ dinv,
                      const float* __restrict__ projw, const float* __restrict__ projb,
                      float* __restrict__ fpk, int N) {
    int wid = (blockIdx.x * blockDim.x + threadIdx.x) >> 6;
    int lane = threadIdx.x & 63;
    if (wid >= N) return;
    const uint* xin2 = (const uint*)xin;
    float dn = dinv[wid];
    uint sv = xin2[(size_t)wid * 64 + lane];
    float wself = dn * dn;
    float acc0 = wself * bflo(sv);
    float acc1 = wself * bfhi(sv);
    int s = offs[wid], e = offs[wid + 1];
    for (int base = s; base < e; base += 64) {
        int idx = base + lane;
        int idxc = min(idx, e - 1);            // always in-bounds, no divergence
        int2 ed = edat[idxc];
        int src = ed.x;
        float ew = (idx < e) ? __int_as_float(ed.y) : 0.f;
        int cnt = min(64, e - base);
        int j = 0;
        for (; j + 4 <= cnt; j += 4) {
            int s0 = __builtin_amdgcn_readlane(src, j);
            int s1 = __builtin_amdgcn_readlane(src, j + 1);
            int s2 = __builtin_amdgcn_readlane(src, j + 2);
            int s3 = __builtin_amdgcn_readlane(src, j + 3);
            float w0 = __int_as_float(__builtin_amdgcn_readlane(__float_as_int(ew), j));
            float w1 = __int_as_float(__builtin_amdgcn_readlane(__float_as_int(ew), j + 1));
            float w2 = __int_as_float(__builtin_amdgcn_readlane(__float_as_int(ew), j + 2));
            float w3 = __int_as_float(__builtin_amdgcn_readlane(__float_as_int(ew), j + 3));
            uint x0 = xin2[(size_t)(uint)s0 * 64 + lane];
            uint x1 = xin2[(size_t)(uint)s1 * 64 + lane];
            uint x2 = xin2[(size_t)(uint)s2 * 64 + lane];
            uint x3 = xin2[(size_t)(uint)s3 * 64 + lane];
            acc0 = fmaf(w0, bflo(x0), acc0); acc1 = fmaf(w0, bfhi(x0), acc1);
            acc0 = fmaf(w1, bflo(x1), acc0); acc1 = fmaf(w1, bfhi(x1), acc1);
            acc0 = fmaf(w2, bflo(x2), acc0); acc1 = fmaf(w2, bfhi(x2), acc1);
            acc0 = fmaf(w3, bflo(x3), acc0); acc1 = fmaf(w3, bfhi(x3), acc1);
        }
        for (; j < cnt; ++j) {
            int sj = __builtin_amdgcn_readlane(src, j);
            float wj = __int_as_float(__builtin_amdgcn_readlane(__float_as_int(ew), j));
            uint xv = xin2[(size_t)(uint)sj * 64 + lane];
            acc0 = fmaf(wj, bflo(xv), acc0);
            acc1 = fmaf(wj, bfhi(xv), acc1);
        }
    }
    ((uint*)xout)[(size_t)wid * 64 + lane] = packbf2(acc0, acc1);
    float dot = acc0 * projw[2 * lane] + acc1 * projw[2 * lane + 1];
#pragma unroll
    for (int m = 1; m < 64; m <<= 1) dot += __shfl_xor(dot, m);
    if (lane == 0) fpk[wid] = dot + projb[0];
}

// ---------------- mean of feature_pool over nodes ----------------
__global__ void k_msum(const float* __restrict__ fp, float* __restrict__ msum, int N) {
    int k = blockIdx.y;
    int i = blockIdx.x * 256 + threadIdx.x;
    int tid = threadIdx.x;
    float v = (i < N) ? fp[(size_t)k * N + i] : 0.f;
#pragma unroll
    for (int m = 1; m < 64; m <<= 1) v += __shfl_xor(v, m);
    __shared__ float ws4[4];
    if ((tid & 63) == 0) ws4[tid >> 6] = v;
    __syncthreads();
    if (tid == 0) atomicAdd(&msum[k], ws4[0] + ws4[1] + ws4[2] + ws4[3]);
}

// ---------------- share_w = l2norm(mean + hop_w) ----------------
__global__ void k_sharew(const float* __restrict__ msum, const float* __restrict__ hopw,
                         float* __restrict__ sharew, int N) {
    int k = threadIdx.x;
    float s = (k < KHOPS + 1) ? (msum[k] / (float)N + hopw[k]) : 0.f;
    float ss = s * s;
#pragma unroll
    for (int m = 1; m < 64; m <<= 1) ss += __shfl_xor(ss, m);
    float inv = 1.f / fmaxf(sqrtf(ss), 1e-12f);
    if (k < KHOPS + 1) sharew[k] = s * inv;
}

// ---------------- final: combine hops, tanh -> LDS (bf16, swizzled), MFMA W2,
//                  log_softmax via 16-lane shfl ----------------
__global__ void k_final(const ushort* __restrict__ hops, const float* __restrict__ fp,
                        const float* __restrict__ sharew, const ushort* __restrict__ w2f,
                        const float* __restrict__ b2, float* __restrict__ out, int N) {
    __shared__ __align__(16) char As[64 * 256];  // 64 nodes x 128 bf16, swizzled 16B slots
    int tid = threadIdx.x;
    int lane = tid & 63, w = tid >> 6;
    int nloc = tid >> 2;                 // 0..63 node within block
    int node = blockIdx.x * 64 + nloc;
    int fg = tid & 3;                    // 16-uint feature chunk
    const uint* hops2 = (const uint*)hops;

    // ---- combine weights c[k] ----
    float c[KHOPS + 1];
    if (node < N) {
        float ss = 0.f;
#pragma unroll
        for (int k = 0; k < KHOPS + 1; ++k) {
            float f = fp[(size_t)k * N + node];
            c[k] = f;
            ss += f * f;
        }
        float inv = 1.f / fmaxf(sqrtf(ss), 1e-12f);
#pragma unroll
        for (int k = 0; k < KHOPS + 1; ++k)
            c[k] = 0.2f * sharew[k] + 0.8f * c[k] * inv;
    } else {
#pragma unroll
        for (int k = 0; k < KHOPS + 1; ++k) c[k] = 0.f;
    }

    // ---- weighted hop combine (32 feats/thread), coalesced uint4 streams ----
    float o[32];
#pragma unroll
    for (int j = 0; j < 32; ++j) o[j] = 0.f;
    if (node < N) {
#pragma unroll
        for (int k = 0; k < KHOPS + 1; ++k) {
            const uint* src = hops2 + ((size_t)k * N + node) * 64 + fg * 16;
#pragma unroll
            for (int i = 0; i < 4; ++i) {
                uint4 v = *(const uint4*)(src + i * 4);
                float ck = c[k];
                o[i * 8 + 0] = fmaf(ck, bflo(v.x), o[i * 8 + 0]);
                o[i * 8 + 1] = fmaf(ck, bfhi(v.x), o[i * 8 + 1]);
                o[i * 8 + 2] = fmaf(ck, bflo(v.y), o[i * 8 + 2]);
                o[i * 8 + 3] = fmaf(ck, bfhi(v.y), o[i * 8 + 3]);
                o[i * 8 + 4] = fmaf(ck, bflo(v.z), o[i * 8 + 4]);
                o[i * 8 + 5] = fmaf(ck, bfhi(v.z), o[i * 8 + 5]);
                o[i * 8 + 6] = fmaf(ck, bflo(v.w), o[i * 8 + 6]);
                o[i * 8 + 7] = fmaf(ck, bfhi(v.w), o[i * 8 + 7]);
            }
        }
    }
    // ---- tanh + pack bf16 -> LDS (slot-XOR swizzle: slot ^= row&15) ----
#pragma unroll
    for (int i = 0; i < 4; ++i) {
        uint4 p;
        p.x = packbf2(tanhf(o[i * 8 + 0]), tanhf(o[i * 8 + 1]));
        p.y = packbf2(tanhf(o[i * 8 + 2]), tanhf(o[i * 8 + 3]));
        p.z = packbf2(tanhf(o[i * 8 + 4]), tanhf(o[i * 8 + 5]));
        p.w = packbf2(tanhf(o[i * 8 + 6]), tanhf(o[i * 8 + 7]));
        int slotbyte = fg * 64 + i * 16;
        int addr = nloc * 256 + (slotbyte ^ ((nloc & 15) << 4));
        *(uint4*)(As + addr) = p;
    }
    __syncthreads();

    // ---- MFMA: M=16 rows/wave, K=128, N=48 (3 tiles) ----
    floatx4 acc[3];
#pragma unroll
    for (int t = 0; t < 3; ++t) acc[t] = (floatx4){0.f, 0.f, 0.f, 0.f};
    int r = w * 16 + (lane & 15);
#pragma unroll
    for (int kk = 0; kk < 4; ++kk) {
        int slotbyte = kk * 64 + (lane >> 4) * 16;
        int addr = r * 256 + (slotbyte ^ ((r & 15) << 4));
        short8 af = *(const short8*)(As + addr);
#pragma unroll
        for (int t = 0; t < 3; ++t) {
            const short8 bf = *(const short8*)(w2f + (size_t)((kk * 3 + t) * 64 + lane) * 8);
            acc[t] = __builtin_amdgcn_mfma_f32_16x16x32_bf16(af, bf, acc[t], 0, 0, 0);
        }
    }

    // ---- epilogue: +b2, log_softmax over 40 classes (cols in lane&15 x 3 tiles) ----
    int cl = lane & 15;
    float b2c[3];
#pragma unroll
    for (int t = 0; t < 3; ++t) {
        int cls = t * 16 + cl;
        b2c[t] = (cls < NC) ? b2[cls] : 0.f;
    }
    bool v2 = cl < 8;  // tile-2 columns 32..39 valid
#pragma unroll
    for (int q = 0; q < 4; ++q) {
        int nodeq = blockIdx.x * 64 + w * 16 + (lane >> 4) * 4 + q;
        float v0 = acc[0][q] + b2c[0];
        float v1 = acc[1][q] + b2c[1];
        float vv2 = acc[2][q] + b2c[2];
        float lm = fmaxf(fmaxf(v0, v1), v2 ? vv2 : -INFINITY);
#pragma unroll
        for (int m = 1; m < 16; m <<= 1) lm = fmaxf(lm, __shfl_xor(lm, m));
        float se = expf(v0 - lm) + expf(v1 - lm) + (v2 ? expf(vv2 - lm) : 0.f);
#pragma unroll
        for (int m = 1; m < 16; m <<= 1) se += __shfl_xor(se, m);
        float lse = lm + logf(se);
        if (nodeq < N) {
            out[(size_t)nodeq * NC + cl] = v0 - lse;
            out[(size_t)nodeq * NC + 16 + cl] = v1 - lse;
            if (v2) out[(size_t)nodeq * NC + 32 + cl] = vv2 - lse;
        }
    }
}

// ---------------- launch ----------------
extern "C" void kernel_launch(void* const* d_in, const int* in_sizes, int n_in,
                              void* d_out, int out_size, void* d_ws, size_t ws_size,
                              hipStream_t stream) {
    const float* x     = (const float*)d_in[0];
    const int*   ei    = (const int*)d_in[1];
    const float* W1    = (const float*)d_in[2];
    const float* b1    = (const float*)d_in[3];
    const float* projw = (const float*)d_in[4];
    const float* projb = (const float*)d_in[5];
    const float* hopw  = (const float*)d_in[6];
    const float* W2    = (const float*)d_in[7];
    const float* b2    = (const float*)d_in[8];
    float* out = (float*)d_out;

    int N = in_sizes[0] / FIN;
    int E = in_sizes[1] / 2;

    char* p = (char*)d_ws;
    auto alloc = [&](size_t bytes) -> char* {
        char* r = p;
        p += (bytes + 255) & ~(size_t)255;
        return r;
    };
    ushort* hops   = (ushort*)alloc((size_t)(KHOPS + 1) * N * HF * 2);
    int*    deg    = (int*)alloc((size_t)N * 4);
    float*  dinv   = (float*)alloc((size_t)N * 4);
    int*    offs   = (int*)alloc((size_t)(N + 1) * 4);
    int*    cursor = (int*)alloc((size_t)N * 4);
    int*    bsum   = (int*)alloc(4096);
    int2*   edat   = (int2*)alloc((size_t)E * 8);
    float*  fp     = (float*)alloc((size_t)(KHOPS + 1) * N * 4);
    float*  msum   = (float*)alloc(64);
    float*  sharew = (float*)alloc(64);
    ushort* w1f    = (ushort*)alloc((size_t)FIN * HF * 2);
    ushort* w2f    = (ushort*)alloc((size_t)12 * 64 * 8 * 2);

    int nb256N = (N + 255) / 256;
    int nbE    = (E + 255) / 256;
    int nbWave = (N + 3) / 4;
    int nb1024 = (N + 1023) / 1024;

    k_w1frag<<<32, 256, 0, stream>>>(W1, w1f);
    k_w2frag<<<3, 256, 0, stream>>>(W2, w2f);
    k_gemm<<<(N + 63) / 64, 256, 0, stream>>>(x, w1f, b1, hops, N);

    k_deg_init<<<nb256N, 256, 0, stream>>>(deg, N);
    k_deg<<<nbE, 256, 0, stream>>>(ei, deg, E);
    k_dinv<<<nb256N, 256, 0, stream>>>(deg, dinv, N);

    k_scan1<<<nb1024, 256, 0, stream>>>(deg, offs, bsum, N);
    k_scan2<<<1, 64, 0, stream>>>(bsum, nb1024);
    k_scan3<<<(N + 256) / 256, 256, 0, stream>>>(offs, bsum, N, E);

    hipMemsetAsync(cursor, 0, (size_t)N * 4, stream);
    k_fill<<<nbE, 256, 0, stream>>>(ei, offs, cursor, edat, dinv, E);

    k_fp0<<<nbWave, 256, 0, stream>>>(hops, projw, projb, fp, N);

    for (int k = 1; k <= KHOPS; ++k) {
        const ushort* xin = hops + (size_t)(k - 1) * N * HF;
        ushort* xout      = hops + (size_t)k * N * HF;
        k_hop<<<nbWave, 256, 0, stream>>>(xin, xout, offs, edat, dinv,
                                          projw, projb, fp + (size_t)k * N, N);
    }

    hipMemsetAsync(msum, 0, 64, stream);
    dim3 gm(nb256N, KHOPS + 1);
    k_msum<<<gm, 256, 0, stream>>>(fp, msum, N);
    k_sharew<<<1, 64, 0, stream>>>(msum, hopw, sharew, N);

    k_final<<<(N + 63) / 64, 256, 0, stream>>>(hops, fp, sharew, w2f, b2, out, N);
}

// Round 3
// 1135.442 us; speedup vs baseline: 1.4178x; 1.0827x over previous
//
#include <hip/hip_runtime.h>

typedef unsigned int uint;
typedef unsigned short ushort;

typedef short short8 __attribute__((ext_vector_type(8)));
typedef float floatx4 __attribute__((ext_vector_type(4)));

#define FIN 512
#define HF  128
#define NC  40
#define KHOPS 10

__device__ __forceinline__ ushort f2bf(float f) {
    uint u = __float_as_uint(f);
    uint r = (u + 0x7fffu + ((u >> 16) & 1u)) >> 16;
    return (ushort)r;
}
__device__ __forceinline__ float bflo(uint v) { return __uint_as_float(v << 16); }
__device__ __forceinline__ float bfhi(uint v) { return __uint_as_float(v & 0xffff0000u); }
__device__ __forceinline__ uint packbf2(float a, float b) {
    return (uint)f2bf(a) | ((uint)f2bf(b) << 16);
}
__device__ __forceinline__ float selu_f(float v) {
    const float l = 1.0507009873554805f, a = 1.6732632423543772f;
    return v > 0.f ? l * v : l * a * (expf(v) - 1.f);
}

// ---------------- W1 -> MFMA fragment layout (bf16) ----------------
__global__ void k_w1frag(const float* __restrict__ W1, ushort* __restrict__ w1f) {
    int id = blockIdx.x * 256 + threadIdx.x;
    if (id >= 16 * 8 * 64) return;
    int l = id & 63;
    int t = (id >> 6) & 7;
    int s = id >> 9;
    int row0 = s * 32 + (l >> 4) * 8;
    int col  = t * 16 + (l & 15);
    ushort* dst = w1f + (size_t)id * 8;
#pragma unroll
    for (int i = 0; i < 8; ++i)
        dst[i] = f2bf(W1[(row0 + i) * HF + col]);
}

// ---------------- W2 -> MFMA fragment layout (bf16, 48-col padded) ----------------
__global__ void k_w2frag(const float* __restrict__ W2, ushort* __restrict__ w2f) {
    int id = blockIdx.x * 256 + threadIdx.x;
    if (id >= 12 * 64) return;
    int l = id & 63;
    int tile = id >> 6;
    int kk = tile / 3, t = tile % 3;
    int row0 = kk * 32 + (l >> 4) * 8;
    int col  = t * 16 + (l & 15);
    ushort* dst = w2f + (size_t)id * 8;
#pragma unroll
    for (int i = 0; i < 8; ++i)
        dst[i] = (col < NC) ? f2bf(W2[(row0 + i) * NC + col]) : (ushort)0;
}

// ---------------- h = selu(x@W1+b1), bf16 out -> hops[0] ----------------
__global__ void k_gemm(const float* __restrict__ x, const ushort* __restrict__ w1f,
                       const float* __restrict__ b1, ushort* __restrict__ h, int N) {
    __shared__ __align__(16) ushort As[64 * 64];
    int tid = threadIdx.x;
    int lane = tid & 63, w = tid >> 6;
    int rowblk = blockIdx.x * 64;

    floatx4 acc[8];
#pragma unroll
    for (int t = 0; t < 8; ++t) acc[t] = (floatx4){0.f, 0.f, 0.f, 0.f};

    for (int kk = 0; kk < 8; ++kk) {
#pragma unroll
        for (int i = 0; i < 4; ++i) {
            int li = tid + 256 * i;
            int r = li >> 4, c4 = li & 15;
            float4 v = make_float4(0.f, 0.f, 0.f, 0.f);
            if (rowblk + r < N)
                v = *(const float4*)(x + (size_t)(rowblk + r) * FIN + kk * 64 + c4 * 4);
            uint p0 = packbf2(v.x, v.y);
            uint p1 = packbf2(v.z, v.w);
            int byteoff = (r * 128 + c4 * 8) ^ ((r & 7) << 4);
            *(uint2*)((char*)As + byteoff) = make_uint2(p0, p1);
        }
        __syncthreads();
        int rowA = w * 16 + (lane & 15);
#pragma unroll
        for (int s = 0; s < 2; ++s) {
            int aoff = (rowA * 128 + s * 64 + (lane >> 4) * 16) ^ ((rowA & 7) << 4);
            short8 af = *(const short8*)((const char*)As + aoff);
#pragma unroll
            for (int t = 0; t < 8; ++t) {
                const short8 bf = *(const short8*)(w1f + ((size_t)((kk * 2 + s) * 8 + t) * 64 + lane) * 8);
                acc[t] = __builtin_amdgcn_mfma_f32_16x16x32_bf16(af, bf, acc[t], 0, 0, 0);
            }
        }
        __syncthreads();
    }
#pragma unroll
    for (int t = 0; t < 8; ++t) {
        int col = t * 16 + (lane & 15);
        float bias = b1[col];
#pragma unroll
        for (int q = 0; q < 4; ++q) {
            int row = rowblk + w * 16 + (lane >> 4) * 4 + q;
            if (row < N) {
                float v = selu_f(acc[t][q] + bias);
                h[(size_t)row * HF + col] = f2bf(v);
            }
        }
    }
}

// ---------------- degree / dinv ----------------
__global__ void k_deg_init(int* __restrict__ deg, int N) {
    int i = blockIdx.x * 256 + threadIdx.x;
    if (i < N) deg[i] = 1;
}
__global__ void k_deg(const int* __restrict__ ei, int* __restrict__ deg, int E) {
    int e = blockIdx.x * 256 + threadIdx.x;
    if (e < E) atomicAdd(&deg[ei[E + e]], 1);
}
__global__ void k_dinv(const int* __restrict__ deg, float* __restrict__ dinv, int N) {
    int i = blockIdx.x * 256 + threadIdx.x;
    if (i < N) dinv[i] = rsqrtf((float)deg[i]);
}

// ---------------- exclusive scan of (deg-1) -> offsets ----------------
__global__ void k_scan1(const int* __restrict__ deg, int* __restrict__ offs,
                        int* __restrict__ bsum, int N) {
    __shared__ int lds[256];
    int tid = threadIdx.x;
    int base = blockIdx.x * 1024;
    int c[4], s = 0;
#pragma unroll
    for (int i = 0; i < 4; ++i) {
        int g = base + tid * 4 + i;
        c[i] = (g < N) ? (deg[g] - 1) : 0;
        s += c[i];
    }
    lds[tid] = s;
    __syncthreads();
    for (int off = 1; off < 256; off <<= 1) {
        int add = (tid >= off) ? lds[tid - off] : 0;
        __syncthreads();
        lds[tid] += add;
        __syncthreads();
    }
    int run = lds[tid] - s;
#pragma unroll
    for (int i = 0; i < 4; ++i) {
        int g = base + tid * 4 + i;
        if (g < N) offs[g] = run;
        run += c[i];
    }
    if (tid == 0) bsum[blockIdx.x] = lds[255];
}
__global__ void k_scan2(int* __restrict__ bsum, int nb) {
    if (blockIdx.x == 0 && threadIdx.x == 0) {
        int run = 0;
        for (int i = 0; i < nb; ++i) { int v = bsum[i]; bsum[i] = run; run += v; }
    }
}
__global__ void k_scan3(int* __restrict__ offs, const int* __restrict__ bsum, int N, int E) {
    int g = blockIdx.x * 256 + threadIdx.x;
    if (g < N) offs[g] += bsum[g >> 10];
    else if (g == N) offs[N] = E;
}

// ---------------- CSR fill: edat = {src, bits(dinv_r*dinv_c)} ----------------
__global__ void k_fill(const int* __restrict__ ei, const int* __restrict__ offs,
                       int* __restrict__ cursor, int2* __restrict__ edat,
                       const float* __restrict__ dinv, int E) {
    int e = blockIdx.x * 256 + threadIdx.x;
    if (e >= E) return;
    int r = ei[e], c = ei[E + e];
    int p = offs[c] + atomicAdd(&cursor[c], 1);
    edat[p] = make_int2(r, __float_as_int(dinv[r] * dinv[c]));
}

// ---------------- feature_pool[0] from h ----------------
__global__ void k_fp0(const ushort* __restrict__ h, const float* __restrict__ projw,
                      const float* __restrict__ projb, float* __restrict__ fp0, int N) {
    int wid = (blockIdx.x * blockDim.x + threadIdx.x) >> 6;
    int lane = threadIdx.x & 63;
    if (wid >= N) return;
    uint v = ((const uint*)h)[(size_t)wid * 64 + lane];
    float dot = bflo(v) * projw[2 * lane] + bfhi(v) * projw[2 * lane + 1];
#pragma unroll
    for (int m = 1; m < 64; m <<= 1) dot += __shfl_xor(dot, m);
    if (lane == 0) fp0[wid] = dot + projb[0];
}

// ---------------- one hop: xn = A_hat @ xc, padded 8-wide gather groups ----
__global__ void k_hop(const ushort* __restrict__ xin, ushort* __restrict__ xout,
                      const int* __restrict__ offs, const int2* __restrict__ edat,
                      const float* __restrict__ dinv,
                      const float* __restrict__ projw, const float* __restrict__ projb,
                      float* __restrict__ fpk, int N) {
    int wid = (blockIdx.x * blockDim.x + threadIdx.x) >> 6;
    int lane = threadIdx.x & 63;
    if (wid >= N) return;
    const uint* xin2 = (const uint*)xin;
    float dn = dinv[wid];
    uint sv = xin2[(size_t)wid * 64 + lane];
    float wself = dn * dn;
    float acc0 = wself * bflo(sv);
    float acc1 = wself * bfhi(sv);
    int s = offs[wid], e = offs[wid + 1];
    for (int base = s; base < e; base += 64) {
        int idx = base + lane;
        int idxc = min(idx, e - 1);
        int2 ed = edat[idxc];
        int src = ed.x;
        float ew = (idx < e) ? __int_as_float(ed.y) : 0.f;
        int cnt = min(64, e - base);
        int groups = (cnt + 7) >> 3;
        for (int g = 0; g < groups; ++g) {
            int j = g * 8;
            int s0 = __builtin_amdgcn_readlane(src, j);
            int s1 = __builtin_amdgcn_readlane(src, j + 1);
            int s2 = __builtin_amdgcn_readlane(src, j + 2);
            int s3 = __builtin_amdgcn_readlane(src, j + 3);
            int s4 = __builtin_amdgcn_readlane(src, j + 4);
            int s5 = __builtin_amdgcn_readlane(src, j + 5);
            int s6 = __builtin_amdgcn_readlane(src, j + 6);
            int s7 = __builtin_amdgcn_readlane(src, j + 7);
            float w0 = __int_as_float(__builtin_amdgcn_readlane(__float_as_int(ew), j));
            float w1 = __int_as_float(__builtin_amdgcn_readlane(__float_as_int(ew), j + 1));
            float w2 = __int_as_float(__builtin_amdgcn_readlane(__float_as_int(ew), j + 2));
            float w3 = __int_as_float(__builtin_amdgcn_readlane(__float_as_int(ew), j + 3));
            float w4 = __int_as_float(__builtin_amdgcn_readlane(__float_as_int(ew), j + 4));
            float w5 = __int_as_float(__builtin_amdgcn_readlane(__float_as_int(ew), j + 5));
            float w6 = __int_as_float(__builtin_amdgcn_readlane(__float_as_int(ew), j + 6));
            float w7 = __int_as_float(__builtin_amdgcn_readlane(__float_as_int(ew), j + 7));
            uint x0 = xin2[(size_t)(uint)s0 * 64 + lane];
            uint x1 = xin2[(size_t)(uint)s1 * 64 + lane];
            uint x2 = xin2[(size_t)(uint)s2 * 64 + lane];
            uint x3 = xin2[(size_t)(uint)s3 * 64 + lane];
            uint x4 = xin2[(size_t)(uint)s4 * 64 + lane];
            uint x5 = xin2[(size_t)(uint)s5 * 64 + lane];
            uint x6 = xin2[(size_t)(uint)s6 * 64 + lane];
            uint x7 = xin2[(size_t)(uint)s7 * 64 + lane];
            acc0 = fmaf(w0, bflo(x0), acc0); acc1 = fmaf(w0, bfhi(x0), acc1);
            acc0 = fmaf(w1, bflo(x1), acc0); acc1 = fmaf(w1, bfhi(x1), acc1);
            acc0 = fmaf(w2, bflo(x2), acc0); acc1 = fmaf(w2, bfhi(x2), acc1);
            acc0 = fmaf(w3, bflo(x3), acc0); acc1 = fmaf(w3, bfhi(x3), acc1);
            acc0 = fmaf(w4, bflo(x4), acc0); acc1 = fmaf(w4, bfhi(x4), acc1);
            acc0 = fmaf(w5, bflo(x5), acc0); acc1 = fmaf(w5, bfhi(x5), acc1);
            acc0 = fmaf(w6, bflo(x6), acc0); acc1 = fmaf(w6, bfhi(x6), acc1);
            acc0 = fmaf(w7, bflo(x7), acc0); acc1 = fmaf(w7, bfhi(x7), acc1);
        }
    }
    ((uint*)xout)[(size_t)wid * 64 + lane] = packbf2(acc0, acc1);
    float dot = acc0 * projw[2 * lane] + acc1 * projw[2 * lane + 1];
#pragma unroll
    for (int m = 1; m < 64; m <<= 1) dot += __shfl_xor(dot, m);
    if (lane == 0) fpk[wid] = dot + projb[0];
}

// ---------------- mean of feature_pool over nodes ----------------
__global__ void k_msum(const float* __restrict__ fp, float* __restrict__ msum, int N) {
    int k = blockIdx.y;
    int i = blockIdx.x * 256 + threadIdx.x;
    int tid = threadIdx.x;
    float v = (i < N) ? fp[(size_t)k * N + i] : 0.f;
#pragma unroll
    for (int m = 1; m < 64; m <<= 1) v += __shfl_xor(v, m);
    __shared__ float ws4[4];
    if ((tid & 63) == 0) ws4[tid >> 6] = v;
    __syncthreads();
    if (tid == 0) atomicAdd(&msum[k], ws4[0] + ws4[1] + ws4[2] + ws4[3]);
}

// ---------------- share_w = l2norm(mean + hop_w) ----------------
__global__ void k_sharew(const float* __restrict__ msum, const float* __restrict__ hopw,
                         float* __restrict__ sharew, int N) {
    int k = threadIdx.x;
    float s = (k < KHOPS + 1) ? (msum[k] / (float)N + hopw[k]) : 0.f;
    float ss = s * s;
#pragma unroll
    for (int m = 1; m < 64; m <<= 1) ss += __shfl_xor(ss, m);
    float inv = 1.f / fmaxf(sqrtf(ss), 1e-12f);
    if (k < KHOPS + 1) sharew[k] = s * inv;
}

// ---------------- final: chunk-major combine (8 accs), tanh -> LDS, MFMA W2,
//                  log_softmax ----------------
__global__ void k_final(const ushort* __restrict__ hops, const float* __restrict__ fp,
                        const float* __restrict__ sharew, const ushort* __restrict__ w2f,
                        const float* __restrict__ b2, float* __restrict__ out, int N) {
    __shared__ __align__(16) char As[64 * 256];  // 64 nodes x 128 bf16, swizzled 16B slots
    int tid = threadIdx.x;
    int lane = tid & 63, w = tid >> 6;
    int nloc = tid >> 2;
    int node = blockIdx.x * 64 + nloc;
    int fg = tid & 3;
    const uint* hops2 = (const uint*)hops;
    bool valid = node < N;
    int nodec = valid ? node : N - 1;

    // ---- combine weights c[k] (fully unrolled -> registers) ----
    float c[KHOPS + 1];
    float ss = 0.f;
#pragma unroll
    for (int k = 0; k <= KHOPS; ++k) {
        float f = fp[(size_t)k * N + nodec];
        c[k] = f;
        ss += f * f;
    }
    float inv = 1.f / fmaxf(sqrtf(ss), 1e-12f);
#pragma unroll
    for (int k = 0; k <= KHOPS; ++k)
        c[k] = valid ? (0.2f * sharew[k] + 0.8f * c[k] * inv) : 0.f;

    // ---- chunk-major weighted combine: 8 accumulators live at a time ----
    const uint* base = hops2 + (size_t)nodec * 64 + fg * 16;
    size_t kstr = (size_t)N * 64;
#pragma unroll 1
    for (int i = 0; i < 4; ++i) {
        float a[8];
#pragma unroll
        for (int j = 0; j < 8; ++j) a[j] = 0.f;
#pragma unroll
        for (int k = 0; k <= KHOPS; ++k) {
            uint4 v = *(const uint4*)(base + (size_t)k * kstr + i * 4);
            float ck = c[k];
            a[0] = fmaf(ck, bflo(v.x), a[0]);
            a[1] = fmaf(ck, bfhi(v.x), a[1]);
            a[2] = fmaf(ck, bflo(v.y), a[2]);
            a[3] = fmaf(ck, bfhi(v.y), a[3]);
            a[4] = fmaf(ck, bflo(v.z), a[4]);
            a[5] = fmaf(ck, bfhi(v.z), a[5]);
            a[6] = fmaf(ck, bflo(v.w), a[6]);
            a[7] = fmaf(ck, bfhi(v.w), a[7]);
        }
        uint4 p;
        p.x = packbf2(tanhf(a[0]), tanhf(a[1]));
        p.y = packbf2(tanhf(a[2]), tanhf(a[3]));
        p.z = packbf2(tanhf(a[4]), tanhf(a[5]));
        p.w = packbf2(tanhf(a[6]), tanhf(a[7]));
        int slotbyte = fg * 64 + i * 16;
        int addr = nloc * 256 + (slotbyte ^ ((nloc & 15) << 4));
        *(uint4*)(As + addr) = p;
    }
    __syncthreads();

    // ---- MFMA: M=16 rows/wave, K=128, N=48 (3 tiles) ----
    floatx4 acc[3];
#pragma unroll
    for (int t = 0; t < 3; ++t) acc[t] = (floatx4){0.f, 0.f, 0.f, 0.f};
    int r = w * 16 + (lane & 15);
#pragma unroll
    for (int kk = 0; kk < 4; ++kk) {
        int slotbyte = kk * 64 + (lane >> 4) * 16;
        int addr = r * 256 + (slotbyte ^ ((r & 15) << 4));
        short8 af = *(const short8*)(As + addr);
#pragma unroll
        for (int t = 0; t < 3; ++t) {
            const short8 bf = *(const short8*)(w2f + (size_t)((kk * 3 + t) * 64 + lane) * 8);
            acc[t] = __builtin_amdgcn_mfma_f32_16x16x32_bf16(af, bf, acc[t], 0, 0, 0);
        }
    }

    // ---- epilogue: +b2, log_softmax over 40 classes ----
    int cl = lane & 15;
    float b2c[3];
#pragma unroll
    for (int t = 0; t < 3; ++t) {
        int cls = t * 16 + cl;
        b2c[t] = (cls < NC) ? b2[cls] : 0.f;
    }
    bool v2 = cl < 8;
#pragma unroll
    for (int q = 0; q < 4; ++q) {
        int nodeq = blockIdx.x * 64 + w * 16 + (lane >> 4) * 4 + q;
        float v0 = acc[0][q] + b2c[0];
        float v1 = acc[1][q] + b2c[1];
        float vv2 = acc[2][q] + b2c[2];
        float lm = fmaxf(fmaxf(v0, v1), v2 ? vv2 : -INFINITY);
#pragma unroll
        for (int m = 1; m < 16; m <<= 1) lm = fmaxf(lm, __shfl_xor(lm, m));
        float se = expf(v0 - lm) + expf(v1 - lm) + (v2 ? expf(vv2 - lm) : 0.f);
#pragma unroll
        for (int m = 1; m < 16; m <<= 1) se += __shfl_xor(se, m);
        float lse = lm + logf(se);
        if (nodeq < N) {
            out[(size_t)nodeq * NC + cl] = v0 - lse;
            out[(size_t)nodeq * NC + 16 + cl] = v1 - lse;
            if (v2) out[(size_t)nodeq * NC + 32 + cl] = vv2 - lse;
        }
    }
}

// ---------------- launch ----------------
extern "C" void kernel_launch(void* const* d_in, const int* in_sizes, int n_in,
                              void* d_out, int out_size, void* d_ws, size_t ws_size,
                              hipStream_t stream) {
    const float* x     = (const float*)d_in[0];
    const int*   ei    = (const int*)d_in[1];
    const float* W1    = (const float*)d_in[2];
    const float* b1    = (const float*)d_in[3];
    const float* projw = (const float*)d_in[4];
    const float* projb = (const float*)d_in[5];
    const float* hopw  = (const float*)d_in[6];
    const float* W2    = (const float*)d_in[7];
    const float* b2    = (const float*)d_in[8];
    float* out = (float*)d_out;

    int N = in_sizes[0] / FIN;
    int E = in_sizes[1] / 2;

    char* p = (char*)d_ws;
    auto alloc = [&](size_t bytes) -> char* {
        char* r = p;
        p += (bytes + 255) & ~(size_t)255;
        return r;
    };
    ushort* hops   = (ushort*)alloc((size_t)(KHOPS + 1) * N * HF * 2);
    int*    deg    = (int*)alloc((size_t)N * 4);
    float*  dinv   = (float*)alloc((size_t)N * 4);
    int*    offs   = (int*)alloc((size_t)(N + 1) * 4);
    int*    cursor = (int*)alloc((size_t)N * 4);
    int*    bsum   = (int*)alloc(4096);
    int2*   edat   = (int2*)alloc((size_t)E * 8);
    float*  fp     = (float*)alloc((size_t)(KHOPS + 1) * N * 4);
    float*  msum   = (float*)alloc(64);
    float*  sharew = (float*)alloc(64);
    ushort* w1f    = (ushort*)alloc((size_t)FIN * HF * 2);
    ushort* w2f    = (ushort*)alloc((size_t)12 * 64 * 8 * 2);

    int nb256N = (N + 255) / 256;
    int nbE    = (E + 255) / 256;
    int nbWave = (N + 3) / 4;
    int nb1024 = (N + 1023) / 1024;

    k_w1frag<<<32, 256, 0, stream>>>(W1, w1f);
    k_w2frag<<<3, 256, 0, stream>>>(W2, w2f);
    k_gemm<<<(N + 63) / 64, 256, 0, stream>>>(x, w1f, b1, hops, N);

    k_deg_init<<<nb256N, 256, 0, stream>>>(deg, N);
    k_deg<<<nbE, 256, 0, stream>>>(ei, deg, E);
    k_dinv<<<nb256N, 256, 0, stream>>>(deg, dinv, N);

    k_scan1<<<nb1024, 256, 0, stream>>>(deg, offs, bsum, N);
    k_scan2<<<1, 64, 0, stream>>>(bsum, nb1024);
    k_scan3<<<(N + 256) / 256, 256, 0, stream>>>(offs, bsum, N, E);

    hipMemsetAsync(cursor, 0, (size_t)N * 4, stream);
    k_fill<<<nbE, 256, 0, stream>>>(ei, offs, cursor, edat, dinv, E);

    k_fp0<<<nbWave, 256, 0, stream>>>(hops, projw, projb, fp, N);

    for (int k = 1; k <= KHOPS; ++k) {
        const ushort* xin = hops + (size_t)(k - 1) * N * HF;
        ushort* xout      = hops + (size_t)k * N * HF;
        k_hop<<<nbWave, 256, 0, stream>>>(xin, xout, offs, edat, dinv,
                                          projw, projb, fp + (size_t)k * N, N);
    }

    hipMemsetAsync(msum, 0, 64, stream);
    dim3 gm(nb256N, KHOPS + 1);
    k_msum<<<gm, 256, 0, stream>>>(fp, msum, N);
    k_sharew<<<1, 64, 0, stream>>>(msum, hopw, sharew, N);

    k_final<<<(N + 63) / 64, 256, 0, stream>>>(hops, fp, sharew, w2f, b2, out, N);
}

// Round 4
// 1009.252 us; speedup vs baseline: 1.5950x; 1.1250x over previous
//
#include <hip/hip_runtime.h>

typedef unsigned int uint;
typedef unsigned short ushort;

typedef short short8 __attribute__((ext_vector_type(8)));
typedef float floatx4 __attribute__((ext_vector_type(4)));

#define FIN 512
#define HF  128
#define NC  40
#define KHOPS 10

__device__ __forceinline__ ushort f2bf(float f) {
    uint u = __float_as_uint(f);
    uint r = (u + 0x7fffu + ((u >> 16) & 1u)) >> 16;
    return (ushort)r;
}
__device__ __forceinline__ float bflo(uint v) { return __uint_as_float(v << 16); }
__device__ __forceinline__ float bfhi(uint v) { return __uint_as_float(v & 0xffff0000u); }
__device__ __forceinline__ uint packbf2(float a, float b) {
    return (uint)f2bf(a) | ((uint)f2bf(b) << 16);
}
__device__ __forceinline__ float selu_f(float v) {
    const float l = 1.0507009873554805f, a = 1.6732632423543772f;
    return v > 0.f ? l * v : l * a * (expf(v) - 1.f);
}

// ---------------- W1 -> MFMA fragment layout (bf16) ----------------
__global__ void k_w1frag(const float* __restrict__ W1, ushort* __restrict__ w1f) {
    int id = blockIdx.x * 256 + threadIdx.x;
    if (id >= 16 * 8 * 64) return;
    int l = id & 63;
    int t = (id >> 6) & 7;
    int s = id >> 9;
    int row0 = s * 32 + (l >> 4) * 8;
    int col  = t * 16 + (l & 15);
    ushort* dst = w1f + (size_t)id * 8;
#pragma unroll
    for (int i = 0; i < 8; ++i)
        dst[i] = f2bf(W1[(row0 + i) * HF + col]);
}

// ---------------- W2 -> MFMA fragment layout (bf16, 48-col padded) ----------------
__global__ void k_w2frag(const float* __restrict__ W2, ushort* __restrict__ w2f) {
    int id = blockIdx.x * 256 + threadIdx.x;
    if (id >= 12 * 64) return;
    int l = id & 63;
    int tile = id >> 6;
    int kk = tile / 3, t = tile % 3;
    int row0 = kk * 32 + (l >> 4) * 8;
    int col  = t * 16 + (l & 15);
    ushort* dst = w2f + (size_t)id * 8;
#pragma unroll
    for (int i = 0; i < 8; ++i)
        dst[i] = (col < NC) ? f2bf(W2[(row0 + i) * NC + col]) : (ushort)0;
}

// ---------------- h = selu(x@W1+b1), bf16 out -> hops[0] ----------------
__global__ void k_gemm(const float* __restrict__ x, const ushort* __restrict__ w1f,
                       const float* __restrict__ b1, ushort* __restrict__ h, int N) {
    __shared__ __align__(16) ushort As[64 * 64];
    int tid = threadIdx.x;
    int lane = tid & 63, w = tid >> 6;
    int rowblk = blockIdx.x * 64;

    floatx4 acc[8];
#pragma unroll
    for (int t = 0; t < 8; ++t) acc[t] = (floatx4){0.f, 0.f, 0.f, 0.f};

    for (int kk = 0; kk < 8; ++kk) {
#pragma unroll
        for (int i = 0; i < 4; ++i) {
            int li = tid + 256 * i;
            int r = li >> 4, c4 = li & 15;
            float4 v = make_float4(0.f, 0.f, 0.f, 0.f);
            if (rowblk + r < N)
                v = *(const float4*)(x + (size_t)(rowblk + r) * FIN + kk * 64 + c4 * 4);
            uint p0 = packbf2(v.x, v.y);
            uint p1 = packbf2(v.z, v.w);
            int byteoff = (r * 128 + c4 * 8) ^ ((r & 7) << 4);
            *(uint2*)((char*)As + byteoff) = make_uint2(p0, p1);
        }
        __syncthreads();
        int rowA = w * 16 + (lane & 15);
#pragma unroll
        for (int s = 0; s < 2; ++s) {
            int aoff = (rowA * 128 + s * 64 + (lane >> 4) * 16) ^ ((rowA & 7) << 4);
            short8 af = *(const short8*)((const char*)As + aoff);
#pragma unroll
            for (int t = 0; t < 8; ++t) {
                const short8 bf = *(const short8*)(w1f + ((size_t)((kk * 2 + s) * 8 + t) * 64 + lane) * 8);
                acc[t] = __builtin_amdgcn_mfma_f32_16x16x32_bf16(af, bf, acc[t], 0, 0, 0);
            }
        }
        __syncthreads();
    }
#pragma unroll
    for (int t = 0; t < 8; ++t) {
        int col = t * 16 + (lane & 15);
        float bias = b1[col];
#pragma unroll
        for (int q = 0; q < 4; ++q) {
            int row = rowblk + w * 16 + (lane >> 4) * 4 + q;
            if (row < N) {
                float v = selu_f(acc[t][q] + bias);
                h[(size_t)row * HF + col] = f2bf(v);
            }
        }
    }
}

// ---------------- degree / dinv ----------------
__global__ void k_deg_init(int* __restrict__ deg, int N) {
    int i = blockIdx.x * 256 + threadIdx.x;
    if (i < N) deg[i] = 1;
}
__global__ void k_deg(const int* __restrict__ ei, int* __restrict__ deg, int E) {
    int e = blockIdx.x * 256 + threadIdx.x;
    if (e < E) atomicAdd(&deg[ei[E + e]], 1);
}
__global__ void k_dinv(const int* __restrict__ deg, float* __restrict__ dinv, int N) {
    int i = blockIdx.x * 256 + threadIdx.x;
    if (i < N) dinv[i] = rsqrtf((float)deg[i]);
}

// ---------------- exclusive scan of (deg-1) -> offsets ----------------
__global__ void k_scan1(const int* __restrict__ deg, int* __restrict__ offs,
                        int* __restrict__ bsum, int N) {
    __shared__ int lds[256];
    int tid = threadIdx.x;
    int base = blockIdx.x * 1024;
    int c[4], s = 0;
#pragma unroll
    for (int i = 0; i < 4; ++i) {
        int g = base + tid * 4 + i;
        c[i] = (g < N) ? (deg[g] - 1) : 0;
        s += c[i];
    }
    lds[tid] = s;
    __syncthreads();
    for (int off = 1; off < 256; off <<= 1) {
        int add = (tid >= off) ? lds[tid - off] : 0;
        __syncthreads();
        lds[tid] += add;
        __syncthreads();
    }
    int run = lds[tid] - s;
#pragma unroll
    for (int i = 0; i < 4; ++i) {
        int g = base + tid * 4 + i;
        if (g < N) offs[g] = run;
        run += c[i];
    }
    if (tid == 0) bsum[blockIdx.x] = lds[255];
}
__global__ void k_scan2(int* __restrict__ bsum, int nb) {
    if (blockIdx.x == 0 && threadIdx.x == 0) {
        int run = 0;
        for (int i = 0; i < nb; ++i) { int v = bsum[i]; bsum[i] = run; run += v; }
    }
}
__global__ void k_scan3(int* __restrict__ offs, const int* __restrict__ bsum, int N, int E) {
    int g = blockIdx.x * 256 + threadIdx.x;
    if (g < N) offs[g] += bsum[g >> 10];
    else if (g == N) offs[N] = E;
}

// ---------------- CSR fill: edat = {src, bits(dinv_r*dinv_c)} ----------------
__global__ void k_fill(const int* __restrict__ ei, const int* __restrict__ offs,
                       int* __restrict__ cursor, int2* __restrict__ edat,
                       const float* __restrict__ dinv, int E) {
    int e = blockIdx.x * 256 + threadIdx.x;
    if (e >= E) return;
    int r = ei[e], c = ei[E + e];
    int p = offs[c] + atomicAdd(&cursor[c], 1);
    edat[p] = make_int2(r, __float_as_int(dinv[r] * dinv[c]));
}

// ---------------- feature_pool[0] from h ----------------
__global__ void k_fp0(const ushort* __restrict__ h, const float* __restrict__ projw,
                      const float* __restrict__ projb, float* __restrict__ fp0, int N) {
    int wid = (blockIdx.x * blockDim.x + threadIdx.x) >> 6;
    int lane = threadIdx.x & 63;
    if (wid >= N) return;
    uint v = ((const uint*)h)[(size_t)wid * 64 + lane];
    float dot = bflo(v) * projw[2 * lane] + bfhi(v) * projw[2 * lane + 1];
#pragma unroll
    for (int m = 1; m < 64; m <<= 1) dot += __shfl_xor(dot, m);
    if (lane == 0) fp0[wid] = dot + projb[0];
}

// ---------------- one hop: xn = A_hat @ xc, 16-deep gather groups ----
__global__ __launch_bounds__(256) void k_hop(
                      const ushort* __restrict__ xin, ushort* __restrict__ xout,
                      const int* __restrict__ offs, const int2* __restrict__ edat,
                      const float* __restrict__ dinv,
                      const float* __restrict__ projw, const float* __restrict__ projb,
                      float* __restrict__ fpk, int N) {
    int wid = (blockIdx.x * blockDim.x + threadIdx.x) >> 6;
    int lane = threadIdx.x & 63;
    if (wid >= N) return;
    const uint* xin2 = (const uint*)xin;
    float dn = dinv[wid];
    uint sv = xin2[(size_t)wid * 64 + lane];
    float wself = dn * dn;
    float acc0 = wself * bflo(sv);
    float acc1 = wself * bfhi(sv);
    int s = offs[wid], e = offs[wid + 1];
    for (int base = s; base < e; base += 64) {
        int idx = base + lane;
        int idxc = min(idx, e - 1);
        int2 ed = edat[idxc];
        int src = ed.x;
        float ew = (idx < e) ? __int_as_float(ed.y) : 0.f;
        int cnt = min(64, e - base);
        int groups = (cnt + 15) >> 4;
        for (int g = 0; g < groups; ++g) {
            int j = g * 16;
            uint xv[16];
            float wv[16];
#pragma unroll
            for (int u = 0; u < 16; ++u) {
                int sj = __builtin_amdgcn_readlane(src, j + u);
                wv[u] = __int_as_float(__builtin_amdgcn_readlane(__float_as_int(ew), j + u));
                xv[u] = xin2[(size_t)(uint)sj * 64 + lane];
            }
#pragma unroll
            for (int u = 0; u < 16; ++u) {
                acc0 = fmaf(wv[u], bflo(xv[u]), acc0);
                acc1 = fmaf(wv[u], bfhi(xv[u]), acc1);
            }
        }
    }
    ((uint*)xout)[(size_t)wid * 64 + lane] = packbf2(acc0, acc1);
    float dot = acc0 * projw[2 * lane] + acc1 * projw[2 * lane + 1];
#pragma unroll
    for (int m = 1; m < 64; m <<= 1) dot += __shfl_xor(dot, m);
    if (lane == 0) fpk[wid] = dot + projb[0];
}

// ---------------- mean of feature_pool over nodes ----------------
__global__ void k_msum(const float* __restrict__ fp, float* __restrict__ msum, int N) {
    int k = blockIdx.y;
    int i = blockIdx.x * 256 + threadIdx.x;
    int tid = threadIdx.x;
    float v = (i < N) ? fp[(size_t)k * N + i] : 0.f;
#pragma unroll
    for (int m = 1; m < 64; m <<= 1) v += __shfl_xor(v, m);
    __shared__ float ws4[4];
    if ((tid & 63) == 0) ws4[tid >> 6] = v;
    __syncthreads();
    if (tid == 0) atomicAdd(&msum[k], ws4[0] + ws4[1] + ws4[2] + ws4[3]);
}

// ---------------- share_w = l2norm(mean + hop_w) ----------------
__global__ void k_sharew(const float* __restrict__ msum, const float* __restrict__ hopw,
                         float* __restrict__ sharew, int N) {
    int k = threadIdx.x;
    float s = (k < KHOPS + 1) ? (msum[k] / (float)N + hopw[k]) : 0.f;
    float ss = s * s;
#pragma unroll
    for (int m = 1; m < 64; m <<= 1) ss += __shfl_xor(ss, m);
    float inv = 1.f / fmaxf(sqrtf(ss), 1e-12f);
    if (k < KHOPS + 1) sharew[k] = s * inv;
}

// ---------------- k_out: 16 nodes/block; single-pass combine (16B/thread),
//                  tanh -> LDS, MFMA K=128 N=48, log_softmax ----------------
__global__ __launch_bounds__(256) void k_out(
                     const ushort* __restrict__ hops, const float* __restrict__ fp,
                     const float* __restrict__ sharew, const ushort* __restrict__ w2f,
                     const float* __restrict__ b2, float* __restrict__ out, int N) {
    __shared__ __align__(16) char As[16 * 256];  // 16 nodes x 128 bf16, swizzled; reused f32 logits
    int tid = threadIdx.x;
    int nloc = tid >> 4;           // 0..15 node in block
    int fg = tid & 15;             // 16B chunk 0..15
    int node = blockIdx.x * 16 + nloc;
    bool valid = node < N;
    int nodec = valid ? node : N - 1;
    const uint* hops2 = (const uint*)hops;

    // ---- combine weights c[k] ----
    float c[KHOPS + 1];
    float ss = 0.f;
#pragma unroll
    for (int k = 0; k <= KHOPS; ++k) {
        float f = fp[(size_t)k * N + nodec];
        c[k] = f;
        ss += f * f;
    }
    float inv = 1.f / fmaxf(sqrtf(ss), 1e-12f);
#pragma unroll
    for (int k = 0; k <= KHOPS; ++k)
        c[k] = valid ? (0.2f * sharew[k] + 0.8f * c[k] * inv) : 0.f;

    // ---- single-pass combine: one contiguous uint4 per hop per thread ----
    const uint* base = hops2 + (size_t)nodec * 64 + fg * 4;
    size_t kstr = (size_t)N * 64;
    float a[8];
#pragma unroll
    for (int j = 0; j < 8; ++j) a[j] = 0.f;
#pragma unroll
    for (int k = 0; k <= KHOPS; ++k) {
        uint4 v = *(const uint4*)(base + (size_t)k * kstr);
        float ck = c[k];
        a[0] = fmaf(ck, bflo(v.x), a[0]);
        a[1] = fmaf(ck, bfhi(v.x), a[1]);
        a[2] = fmaf(ck, bflo(v.y), a[2]);
        a[3] = fmaf(ck, bfhi(v.y), a[3]);
        a[4] = fmaf(ck, bflo(v.z), a[4]);
        a[5] = fmaf(ck, bfhi(v.z), a[5]);
        a[6] = fmaf(ck, bflo(v.w), a[6]);
        a[7] = fmaf(ck, bfhi(v.w), a[7]);
    }
    uint4 pk;
    pk.x = packbf2(tanhf(a[0]), tanhf(a[1]));
    pk.y = packbf2(tanhf(a[2]), tanhf(a[3]));
    pk.z = packbf2(tanhf(a[4]), tanhf(a[5]));
    pk.w = packbf2(tanhf(a[6]), tanhf(a[7]));
    {
        int slotbyte = fg * 16;
        int addr = nloc * 256 + (slotbyte ^ ((nloc & 15) << 4));
        *(uint4*)(As + addr) = pk;
    }
    __syncthreads();

    // ---- MFMA: 16 rows, K=128, N=48; wave w (0..2) does N-tile w ----
    int w = tid >> 6, lane = tid & 63;
    floatx4 acc = (floatx4){0.f, 0.f, 0.f, 0.f};
    if (w < 3) {
        int r = lane & 15;
#pragma unroll
        for (int kk = 0; kk < 4; ++kk) {
            int slotbyte = kk * 64 + (lane >> 4) * 16;
            int addr = r * 256 + (slotbyte ^ ((r & 15) << 4));
            short8 af = *(const short8*)(As + addr);
            const short8 bf = *(const short8*)(w2f + (size_t)((kk * 3 + w) * 64 + lane) * 8);
            acc = __builtin_amdgcn_mfma_f32_16x16x32_bf16(af, bf, acc, 0, 0, 0);
        }
    }
    __syncthreads();  // done reading As; reuse as logits

    float* Ls = (float*)As;  // [16][48]
    if (w < 3) {
        int cls = w * 16 + (lane & 15);
        float bb = (cls < NC) ? b2[cls] : 0.f;
#pragma unroll
        for (int q = 0; q < 4; ++q) {
            int row = (lane >> 4) * 4 + q;
            Ls[row * 48 + cls] = acc[q] + bb;
        }
    }
    __syncthreads();

    // ---- log-softmax: 16 threads per row ----
    int r2 = tid >> 4;       // row 0..15
    int c16 = tid & 15;
    float v0 = Ls[r2 * 48 + c16];
    float v1 = Ls[r2 * 48 + 16 + c16];
    bool has2 = c16 < 8;
    float v2 = has2 ? Ls[r2 * 48 + 32 + c16] : -INFINITY;
    float lm = fmaxf(fmaxf(v0, v1), v2);
#pragma unroll
    for (int m = 1; m < 16; m <<= 1) lm = fmaxf(lm, __shfl_xor(lm, m));
    float se = expf(v0 - lm) + expf(v1 - lm) + (has2 ? expf(v2 - lm) : 0.f);
#pragma unroll
    for (int m = 1; m < 16; m <<= 1) se += __shfl_xor(se, m);
    float lse = lm + logf(se);
    int nodeo = blockIdx.x * 16 + r2;
    if (nodeo < N) {
        out[(size_t)nodeo * NC + c16] = v0 - lse;
        out[(size_t)nodeo * NC + 16 + c16] = v1 - lse;
        if (has2) out[(size_t)nodeo * NC + 32 + c16] = v2 - lse;
    }
}

// ---------------- launch ----------------
extern "C" void kernel_launch(void* const* d_in, const int* in_sizes, int n_in,
                              void* d_out, int out_size, void* d_ws, size_t ws_size,
                              hipStream_t stream) {
    const float* x     = (const float*)d_in[0];
    const int*   ei    = (const int*)d_in[1];
    const float* W1    = (const float*)d_in[2];
    const float* b1    = (const float*)d_in[3];
    const float* projw = (const float*)d_in[4];
    const float* projb = (const float*)d_in[5];
    const float* hopw  = (const float*)d_in[6];
    const float* W2    = (const float*)d_in[7];
    const float* b2    = (const float*)d_in[8];
    float* out = (float*)d_out;

    int N = in_sizes[0] / FIN;
    int E = in_sizes[1] / 2;

    char* p = (char*)d_ws;
    auto alloc = [&](size_t bytes) -> char* {
        char* r = p;
        p += (bytes + 255) & ~(size_t)255;
        return r;
    };
    ushort* hops   = (ushort*)alloc((size_t)(KHOPS + 1) * N * HF * 2);
    int*    deg    = (int*)alloc((size_t)N * 4);
    float*  dinv   = (float*)alloc((size_t)N * 4);
    int*    offs   = (int*)alloc((size_t)(N + 1) * 4);
    int*    cursor = (int*)alloc((size_t)N * 4);
    int*    bsum   = (int*)alloc(4096);
    int2*   edat   = (int2*)alloc((size_t)E * 8);
    float*  fp     = (float*)alloc((size_t)(KHOPS + 1) * N * 4);
    float*  msum   = (float*)alloc(64);
    float*  sharew = (float*)alloc(64);
    ushort* w1f    = (ushort*)alloc((size_t)FIN * HF * 2);
    ushort* w2f    = (ushort*)alloc((size_t)12 * 64 * 8 * 2);

    int nb256N = (N + 255) / 256;
    int nbE    = (E + 255) / 256;
    int nbWave = (N + 3) / 4;
    int nb1024 = (N + 1023) / 1024;

    k_w1frag<<<32, 256, 0, stream>>>(W1, w1f);
    k_w2frag<<<3, 256, 0, stream>>>(W2, w2f);
    k_gemm<<<(N + 63) / 64, 256, 0, stream>>>(x, w1f, b1, hops, N);

    k_deg_init<<<nb256N, 256, 0, stream>>>(deg, N);
    k_deg<<<nbE, 256, 0, stream>>>(ei, deg, E);
    k_dinv<<<nb256N, 256, 0, stream>>>(deg, dinv, N);

    k_scan1<<<nb1024, 256, 0, stream>>>(deg, offs, bsum, N);
    k_scan2<<<1, 64, 0, stream>>>(bsum, nb1024);
    k_scan3<<<(N + 256) / 256, 256, 0, stream>>>(offs, bsum, N, E);

    hipMemsetAsync(cursor, 0, (size_t)N * 4, stream);
    k_fill<<<nbE, 256, 0, stream>>>(ei, offs, cursor, edat, dinv, E);

    k_fp0<<<nbWave, 256, 0, stream>>>(hops, projw, projb, fp, N);

    for (int k = 1; k <= KHOPS; ++k) {
        const ushort* xin = hops + (size_t)(k - 1) * N * HF;
        ushort* xout      = hops + (size_t)k * N * HF;
        k_hop<<<nbWave, 256, 0, stream>>>(xin, xout, offs, edat, dinv,
                                          projw, projb, fp + (size_t)k * N, N);
    }

    hipMemsetAsync(msum, 0, 64, stream);
    dim3 gm(nb256N, KHOPS + 1);
    k_msum<<<gm, 256, 0, stream>>>(fp, msum, N);
    k_sharew<<<1, 64, 0, stream>>>(msum, hopw, sharew, N);

    k_out<<<(N + 15) / 16, 256, 0, stream>>>(hops, fp, sharew, w2f, b2, out, N);
}